// Round 4
// baseline (569.208 us; speedup 1.0000x reference)
//
#include <hip/hip_runtime.h>

// Longformer BART encoder layer on MI355X — bf16 MFMA, 8-phase 256-tile GEMMs.
// B=2 S=4096 D=1024 H=16 HD=64 FFN=4096 one-sided window=256.

typedef unsigned short ushort_t;
typedef unsigned char uchar_t;
typedef __attribute__((ext_vector_type(8))) short bf16x8;   // 8 bf16 = 4 VGPR
typedef __attribute__((ext_vector_type(4))) float f32x4;

constexpr int CB  = 2;
constexpr int CS  = 4096;
constexpr int CD  = 1024;
constexpr int CH  = 16;
constexpr int CHD = 64;
constexpr int CF  = 4096;
constexpr int CM  = CB * CS;      // 8192
constexpr float NEGV = -1e9f;

__device__ __forceinline__ ushort_t f2bf(float f) {
  unsigned u = __float_as_uint(f);
  unsigned r = u + 0x7FFFu + ((u >> 16) & 1u);   // RNE
  return (ushort_t)(r >> 16);
}
__device__ __forceinline__ float gelu_exact(float x) {
  return 0.5f * x * (1.0f + erff(x * 0.70710678118654752f));
}

// ---- swizzled ds_read_b128 of one bf16x8 fragment (rows of 64 bf16 = 128 B,
// 8 slots of 16 B, physical slot = logical slot ^ (row&7)).
__device__ __forceinline__ bf16x8 ldsfrag(const char* lds, int row, int slot) {
  return *(const bf16x8*)(lds + row * 128 + (((slot ^ (row & 7)) << 4)));
}

// ---- 256-thread staging (attention): NROWS x 64-bf16 tile, pre-swizzled source.
template <int NROWS>
__device__ __forceinline__ void stage_swz(const ushort_t* __restrict__ src, int stride,
                                          char* lds, int tid) {
  const int lane = tid & 63, w = tid >> 6;
#pragma unroll
  for (int it = 0; it < NROWS / 32; ++it) {
    const int o   = it * 4096 + w * 1024;        // wave-uniform LDS byte base
    const int eo  = o + lane * 16;
    const int row = eo >> 7;
    const int lslot = ((eo >> 4) & 7) ^ (row & 7);
    const ushort_t* g = src + (size_t)row * stride + lslot * 8;
    __builtin_amdgcn_global_load_lds((const __attribute__((address_space(1))) void*)g,
                                     (__attribute__((address_space(3))) void*)(lds + o),
                                     16, 0, 0);
  }
}

// ---- 512-thread staging: one 64-row chunk (8 KB) of a [256|128]x64-bf16 tile.
__device__ __forceinline__ void stageC(const ushort_t* __restrict__ gtile, int ldK,
                                       char* ldsT, int chunk, int tid) {
  const int eo   = chunk * 8192 + tid * 16;
  const int row  = eo >> 7;
  const int slot = ((eo >> 4) & 7) ^ (row & 7);
  __builtin_amdgcn_global_load_lds(
      (const __attribute__((address_space(1))) void*)(gtile + (size_t)row * ldK + slot * 8),
      (__attribute__((address_space(3))) void*)(ldsT + eo), 16, 0, 0);
}

// ---- one phase of the 8-phase schedule: ds_read quadrant frags; issue stage;
// barrier; lgkmcnt(0); setprio(1)+MFMA; [counted vmcnt]; barrier.
template <int MH, int NH, int NPH, int NF, int VM, typename F>
__device__ __forceinline__ void phase8(const char* Ax, const char* Bx,
                                       int wr, int wc, int rl, int kl,
                                       f32x4 (&acc)[8][NF], F stage) {
  bf16x8 af[4][2], bfr[NPH][2];
#pragma unroll
  for (int mf = 0; mf < 4; ++mf)
#pragma unroll
    for (int kk = 0; kk < 2; ++kk)
      af[mf][kk] = ldsfrag(Ax, wr * 128 + (MH * 4 + mf) * 16 + rl, kk * 4 + kl);
#pragma unroll
  for (int nf = 0; nf < NPH; ++nf)
#pragma unroll
    for (int kk = 0; kk < 2; ++kk)
      bfr[nf][kk] = ldsfrag(Bx, wc * (NF * 16) + (NH * NPH + nf) * 16 + rl, kk * 4 + kl);
  stage();
  __builtin_amdgcn_s_barrier();
  asm volatile("s_waitcnt lgkmcnt(0)" ::: "memory");
  __builtin_amdgcn_s_setprio(1);
#pragma unroll
  for (int mf = 0; mf < 4; ++mf)
#pragma unroll
    for (int nf = 0; nf < NPH; ++nf)
#pragma unroll
      for (int kk = 0; kk < 2; ++kk)
        acc[MH * 4 + mf][NH * NPH + nf] = __builtin_amdgcn_mfma_f32_16x16x32_bf16(
            af[mf][kk], bfr[nf][kk], acc[MH * 4 + mf][NH * NPH + nf], 0, 0, 0);
  __builtin_amdgcn_s_setprio(0);
  if constexpr (VM == 1) asm volatile("s_waitcnt vmcnt(2)" ::: "memory");
  if constexpr (VM == 2) asm volatile("s_waitcnt vmcnt(0)" ::: "memory");
  __builtin_amdgcn_s_barrier();
}

// ---- 256xBNxK mainloop, 8 waves (2x4), double-buffered LDS, counted-vmcnt pipeline.
// Stage schedule (derived; every chunk staged strictly after its region is dead):
//  BN=256: q1:A1A3(m+1)  q2:B01(m+1)  q3:B23(m+1)  q4:A0A2(m+2)+vmcnt(2)
//  BN=128: p1:A1A3(m+1)+B0(m+1)       p2:B1(m+1)+A0A2(m+2)+vmcnt(2)
template <int BN>
__device__ __forceinline__ void run_mainloop(const ushort_t* __restrict__ A,
                                             const ushort_t* __restrict__ Bt,
                                             int K, int bm, int bn, char* lds, int tid,
                                             f32x4 (&acc)[8][BN / 64]) {
  constexpr int NF = BN / 64;
  char* Ab0 = lds;
  char* Bb0 = lds + 32768;
  char* Ab1 = lds + 32768 + BN * 128;
  char* Bb1 = Ab1 + 32768;
  const int lane = tid & 63, wid = tid >> 6;
  const int wr = wid >> 2, wc = wid & 3, rl = lane & 15, kl = lane >> 4;
  const ushort_t* Ao = A + (size_t)bm * K;
  const ushort_t* Bo = Bt + (size_t)bn * K;
  const int NT = K >> 6;
  // prologue: tile0 full + A0,A2 of tile1; keep 2 loads in flight
#pragma unroll
  for (int c = 0; c < 4; ++c) stageC(Ao, K, Ab0, c, tid);
#pragma unroll
  for (int c = 0; c < NF; ++c) stageC(Bo, K, Bb0, c, tid);
  if (NT > 1) {
    stageC(Ao + 64, K, Ab1, 0, tid);
    stageC(Ao + 64, K, Ab1, 2, tid);
    asm volatile("s_waitcnt vmcnt(2)" ::: "memory");
  } else {
    asm volatile("s_waitcnt vmcnt(0)" ::: "memory");
  }
  __builtin_amdgcn_s_barrier();

  for (int m = 0; m < NT; ++m) {
    const int p = m & 1;
    char* Ax = p ? Ab1 : Ab0;  char* Bx = p ? Bb1 : Bb0;
    char* Axn = p ? Ab0 : Ab1; char* Bxn = p ? Bb0 : Bb1;
    const bool s1 = (m + 1 < NT), s2 = (m + 2 < NT);
    const ushort_t* An1 = Ao + (m + 1) * 64;
    const ushort_t* Bn1 = Bo + (m + 1) * 64;
    const ushort_t* An2 = Ao + (m + 2) * 64;
    if constexpr (NF == 4) {
      phase8<0, 0, 2, 4, 0>(Ax, Bx, wr, wc, rl, kl, acc, [&] {
        if (s1) { stageC(An1, K, Axn, 1, tid); stageC(An1, K, Axn, 3, tid); } });
      phase8<0, 1, 2, 4, 0>(Ax, Bx, wr, wc, rl, kl, acc, [&] {
        if (s1) { stageC(Bn1, K, Bxn, 0, tid); stageC(Bn1, K, Bxn, 1, tid); } });
      phase8<1, 0, 2, 4, 0>(Ax, Bx, wr, wc, rl, kl, acc, [&] {
        if (s1) { stageC(Bn1, K, Bxn, 2, tid); stageC(Bn1, K, Bxn, 3, tid); } });
      if (s2)      phase8<1, 1, 2, 4, 1>(Ax, Bx, wr, wc, rl, kl, acc, [&] {
        stageC(An2, K, Ax, 0, tid); stageC(An2, K, Ax, 2, tid); });
      else if (s1) phase8<1, 1, 2, 4, 2>(Ax, Bx, wr, wc, rl, kl, acc, [&] {});
      else         phase8<1, 1, 2, 4, 0>(Ax, Bx, wr, wc, rl, kl, acc, [&] {});
    } else {
      phase8<0, 0, 2, 2, 0>(Ax, Bx, wr, wc, rl, kl, acc, [&] {
        if (s1) { stageC(An1, K, Axn, 1, tid); stageC(An1, K, Axn, 3, tid);
                  stageC(Bn1, K, Bxn, 0, tid); } });
      if (s2)      phase8<1, 0, 2, 2, 1>(Ax, Bx, wr, wc, rl, kl, acc, [&] {
        stageC(Bn1, K, Bxn, 1, tid);
        stageC(An2, K, Ax, 0, tid); stageC(An2, K, Ax, 2, tid); });
      else if (s1) phase8<1, 0, 2, 2, 2>(Ax, Bx, wr, wc, rl, kl, acc, [&] {
        stageC(Bn1, K, Bxn, 1, tid); });
      else         phase8<1, 0, 2, 2, 0>(Ax, Bx, wr, wc, rl, kl, acc, [&] {});
    }
  }
}

// ---------------- generic 8-wave GEMM with epilogues
// EPI 1: fp32 out = acc + bias + res(fp32).  EPI 2: bf16 out = gelu(acc + bias).
template <int BN, int EPI>
__global__ __launch_bounds__(512, 1) void gemm8(
    const ushort_t* __restrict__ A, const ushort_t* __restrict__ Bt,
    const float* __restrict__ bias, const float* __restrict__ res,
    float* __restrict__ outF, ushort_t* __restrict__ outB, int N, int K) {
  constexpr int NF = BN / 64;
  __shared__ __align__(16) char lds[2 * (32768 + BN * 128)];
  const int tid = threadIdx.x;
  const int bm = blockIdx.x * 256, bn = blockIdx.y * BN;
  f32x4 acc[8][NF] = {};
  run_mainloop<BN>(A, Bt, K, bm, bn, lds, tid, acc);
  const int lane = tid & 63, wid = tid >> 6;
  const int wr = wid >> 2, wc = wid & 3, rl = lane & 15, kl = lane >> 4;
#pragma unroll
  for (int mf = 0; mf < 8; ++mf) {
    const int r0 = bm + wr * 128 + mf * 16 + kl * 4;
#pragma unroll
    for (int nf = 0; nf < NF; ++nf) {
      const int col = bn + wc * (NF * 16) + nf * 16 + rl;
      const float bb = bias[col];
#pragma unroll
      for (int i = 0; i < 4; ++i) {
        float v = acc[mf][nf][i] + bb;
        if (EPI == 1) {
          v += res[(size_t)(r0 + i) * N + col];
          outF[(size_t)(r0 + i) * N + col] = v;
        } else {
          outB[(size_t)(r0 + i) * N + col] = f2bf(gelu_exact(v));
        }
      }
    }
  }
}

// ---------------- QKV projection (BN=128): q,k [B,H,S,64] bf16 (q pre-scaled), v^T [B,H,64,S]
__global__ __launch_bounds__(512, 1) void qkv8(
    const ushort_t* __restrict__ hsb,
    const ushort_t* __restrict__ WqT, const ushort_t* __restrict__ WkT,
    const ushort_t* __restrict__ WvT,
    const float* __restrict__ bq, const float* __restrict__ bk, const float* __restrict__ bv,
    ushort_t* __restrict__ q, ushort_t* __restrict__ k, ushort_t* __restrict__ vt) {
  __shared__ __align__(16) char lds[2 * (32768 + 16384)];
  const int tid = threadIdx.x;
  const int which = blockIdx.z;
  const ushort_t* Wt = (which == 0) ? WqT : (which == 1) ? WkT : WvT;
  const float* bia   = (which == 0) ? bq  : (which == 1) ? bk  : bv;
  const float mul    = (which == 0) ? 0.125f : 1.0f;
  const int bm = blockIdx.x * 256, bn = blockIdx.y * 128;
  f32x4 acc[8][2] = {};
  run_mainloop<128>(hsb, Wt, CD, bm, bn, lds, tid, acc);
  const int lane = tid & 63, wid = tid >> 6;
  const int wr = wid >> 2, wc = wid & 3, rl = lane & 15, kl = lane >> 4;
#pragma unroll
  for (int mf = 0; mf < 8; ++mf) {
    const int r0 = bm + wr * 128 + mf * 16 + kl * 4;
    const int bidx = r0 >> 12;
    const int s0 = r0 & (CS - 1);
#pragma unroll
    for (int nf = 0; nf < 2; ++nf) {
      const int col = bn + wc * 32 + nf * 16 + rl;
      const int h = col >> 6, hd = col & 63;
      const float bb = bia[col];
      if (which < 2) {
        ushort_t* dst = (which == 0 ? q : k);
#pragma unroll
        for (int i = 0; i < 4; ++i) {
          const float v = (acc[mf][nf][i] + bb) * mul;
          dst[((((size_t)bidx * CH + h) * CS) + s0 + i) * CHD + hd] = f2bf(v);
        }
      } else {
        ushort4 o;
        o.x = f2bf(acc[mf][nf][0] + bb); o.y = f2bf(acc[mf][nf][1] + bb);
        o.z = f2bf(acc[mf][nf][2] + bb); o.w = f2bf(acc[mf][nf][3] + bb);
        *(ushort4*)&vt[(((size_t)bidx * CH + h) * CHD + hd) * CS + s0] = o;
      }
    }
  }
}

// ---------------- cast fp32 -> bf16 (flat)
__global__ __launch_bounds__(256) void cast_bf16(const float* __restrict__ x,
                                                 ushort_t* __restrict__ y) {
  const size_t i = ((size_t)blockIdx.x * 256 + threadIdx.x) * 4;
  const float4 v = *(const float4*)(x + i);
  ushort4 o;
  o.x = f2bf(v.x); o.y = f2bf(v.y); o.z = f2bf(v.z); o.w = f2bf(v.w);
  *(ushort4*)(y + i) = o;
}

// ---------------- W [K][N] fp32 -> Wt [N][K] bf16
__global__ __launch_bounds__(256) void transpose_cast(const float* __restrict__ W,
                                                      ushort_t* __restrict__ Wt,
                                                      int K, int N) {
  __shared__ float t[64][65];
  const int k0 = blockIdx.x * 64, n0 = blockIdx.y * 64;
  const int ty = threadIdx.x >> 4, tx = threadIdx.x & 15;
#pragma unroll
  for (int rr = 0; rr < 4; ++rr) {
    const int r = rr * 16 + ty;
    const float4 v = *(const float4*)&W[(size_t)(k0 + r) * N + n0 + tx * 4];
    t[r][tx * 4 + 0] = v.x; t[r][tx * 4 + 1] = v.y;
    t[r][tx * 4 + 2] = v.z; t[r][tx * 4 + 3] = v.w;
  }
  __syncthreads();
#pragma unroll
  for (int rr = 0; rr < 4; ++rr) {
    const int rn = rr * 16 + ty;
    ushort4 o;
    o.x = f2bf(t[tx * 4 + 0][rn]); o.y = f2bf(t[tx * 4 + 1][rn]);
    o.z = f2bf(t[tx * 4 + 2][rn]); o.w = f2bf(t[tx * 4 + 3][rn]);
    *(ushort4*)&Wt[(size_t)(n0 + rn) * K + k0 + tx * 4] = o;
  }
}

// ---------------- banded attention, MFMA flash-style (4 waves).
__global__ __launch_bounds__(256) void attn_mfma(
    const ushort_t* __restrict__ qg, const ushort_t* __restrict__ kg,
    const ushort_t* __restrict__ vtg,
    const float* __restrict__ amask, const uchar_t* __restrict__ qmask,
    const float* __restrict__ hmask, ushort_t* __restrict__ outb) {
  __shared__ __align__(16) char Qs[8192];
  __shared__ __align__(16) char Ks[8192];
  __shared__ __align__(16) char Vt[8192];
  __shared__ __align__(16) char Ps[8192];
  const int qt0 = blockIdx.x * 64, h = blockIdx.y, b = blockIdx.z;
  const int tid = threadIdx.x, lane = tid & 63, w = tid >> 6;
  const size_t bh = (size_t)b * CH + h;

  stage_swz<64>(qg + (bh * CS + qt0) * CHD, CHD, Qs, tid);

  f32x4 O[4] = {};
  float m_run[4], l_run[4];
#pragma unroll
  for (int i = 0; i < 4; ++i) { m_run[i] = -INFINITY; l_run[i] = 0.f; }

  for (int c = 0; c < 9; ++c) {
    const int k0 = qt0 - 256 + c * 64;
    if (k0 < 0 || k0 >= CS) continue;
    __syncthreads();
    stage_swz<64>(kg + (bh * CS + k0) * CHD, CHD, Ks, tid);
    stage_swz<64>(vtg + bh * CHD * CS + k0, CS, Vt, tid);
    __syncthreads();

    f32x4 s[4] = {};
#pragma unroll
    for (int kk = 0; kk < 2; ++kk) {
      const bf16x8 a = ldsfrag(Qs, w * 16 + (lane & 15), kk * 4 + (lane >> 4));
#pragma unroll
      for (int n = 0; n < 4; ++n) {
        const bf16x8 bb = ldsfrag(Ks, n * 16 + (lane & 15), kk * 4 + (lane >> 4));
        s[n] = __builtin_amdgcn_mfma_f32_16x16x32_bf16(a, bb, s[n], 0, 0, 0);
      }
    }

    float kmv[4]; int keyc[4];
#pragma unroll
    for (int n = 0; n < 4; ++n) {
      keyc[n] = k0 + n * 16 + (lane & 15);
      kmv[n] = amask[(size_t)b * CS + keyc[n]];
    }
    const int qrb = qt0 + w * 16 + ((lane >> 4) << 2);
#pragma unroll
    for (int i = 0; i < 4; ++i) {
      const int qi = qrb + i;
      float mx = -INFINITY;
#pragma unroll
      for (int n = 0; n < 4; ++n) {
        const int d = keyc[n] - qi;
        float x = (d <= 256 && d >= -256) ? (s[n][i] + kmv[n]) : NEGV;
        s[n][i] = x;
        mx = fmaxf(mx, x);
      }
      mx = fmaxf(mx, __shfl_xor(mx, 1));
      mx = fmaxf(mx, __shfl_xor(mx, 2));
      mx = fmaxf(mx, __shfl_xor(mx, 4));
      mx = fmaxf(mx, __shfl_xor(mx, 8));
      const float m_new = fmaxf(m_run[i], mx);
      const float scf = expf(m_run[i] - m_new);
      float rs = 0.f;
#pragma unroll
      for (int n = 0; n < 4; ++n) {
        const float p = expf(s[n][i] - m_new);
        s[n][i] = p;
        rs += p;
      }
      rs += __shfl_xor(rs, 1); rs += __shfl_xor(rs, 2);
      rs += __shfl_xor(rs, 4); rs += __shfl_xor(rs, 8);
      l_run[i] = l_run[i] * scf + rs;
      m_run[i] = m_new;
#pragma unroll
      for (int n = 0; n < 4; ++n) O[n][i] *= scf;
      const int prow = w * 16 + ((lane >> 4) << 2) + i;
#pragma unroll
      for (int n = 0; n < 4; ++n) {
        const int pcol = n * 16 + (lane & 15);
        const int byte = prow * 128 + ((((pcol >> 3) ^ (prow & 7)) << 4)) + ((pcol & 7) << 1);
        *(ushort_t*)(Ps + byte) = f2bf(s[n][i]);
      }
    }
    __syncthreads();

#pragma unroll
    for (int kk = 0; kk < 2; ++kk) {
      const bf16x8 pa = ldsfrag(Ps, w * 16 + (lane & 15), kk * 4 + (lane >> 4));
#pragma unroll
      for (int nd = 0; nd < 4; ++nd) {
        const bf16x8 vv = ldsfrag(Vt, nd * 16 + (lane & 15), kk * 4 + (lane >> 4));
        O[nd] = __builtin_amdgcn_mfma_f32_16x16x32_bf16(pa, vv, O[nd], 0, 0, 0);
      }
    }
  }

  const float hm = hmask[h];
#pragma unroll
  for (int i = 0; i < 4; ++i) {
    const int qi = qt0 + w * 16 + ((lane >> 4) << 2) + i;
    const bool qm = qmask[(size_t)b * CS + qi] != 0;
    const float scl = (qm ? 0.f : hm) / fmaxf(l_run[i], 1e-30f);
#pragma unroll
    for (int nd = 0; nd < 4; ++nd) {
      const int col = h * CHD + nd * 16 + (lane & 15);
      outb[((size_t)b * CS + qi) * CD + col] = f2bf(O[nd][i] * scl);
    }
  }
}

// ---------------- LayerNorm over D=1024; optional bf16 secondary output
__global__ __launch_bounds__(256) void ln_f32(const float* __restrict__ X,
                                              const float* __restrict__ g,
                                              const float* __restrict__ bt,
                                              float* __restrict__ Y,
                                              ushort_t* __restrict__ Yb) {
  const int row = blockIdx.x;
  const int tid = threadIdx.x;
  const float4 xv = *(const float4*)(X + (size_t)row * CD + (tid << 2));
  float s  = xv.x + xv.y + xv.z + xv.w;
  float s2 = xv.x * xv.x + xv.y * xv.y + xv.z * xv.z + xv.w * xv.w;
#pragma unroll
  for (int off = 32; off; off >>= 1) {
    s  += __shfl_xor(s, off);
    s2 += __shfl_xor(s2, off);
  }
  __shared__ float red[8];
  const int wv = tid >> 6;
  if ((tid & 63) == 0) { red[wv] = s; red[wv + 4] = s2; }
  __syncthreads();
  s  = red[0] + red[1] + red[2] + red[3];
  s2 = red[4] + red[5] + red[6] + red[7];
  const float mean = s * (1.f / CD);
  const float var  = s2 * (1.f / CD) - mean * mean;
  const float r = rsqrtf(var + 1e-5f);
  const float4 gv = *(const float4*)(g + (tid << 2));
  const float4 bv = *(const float4*)(bt + (tid << 2));
  float4 o;
  o.x = (xv.x - mean) * r * gv.x + bv.x;
  o.y = (xv.y - mean) * r * gv.y + bv.y;
  o.z = (xv.z - mean) * r * gv.z + bv.z;
  o.w = (xv.w - mean) * r * gv.w + bv.w;
  *(float4*)(Y + (size_t)row * CD + (tid << 2)) = o;
  if (Yb) {
    ushort4 ob;
    ob.x = f2bf(o.x); ob.y = f2bf(o.y); ob.z = f2bf(o.z); ob.w = f2bf(o.w);
    *(ushort4*)(Yb + (size_t)row * CD + (tid << 2)) = ob;
  }
}

extern "C" void kernel_launch(void* const* d_in, const int* in_sizes, int n_in,
                              void* d_out, int out_size, void* d_ws, size_t ws_size,
                              hipStream_t stream) {
  const float* hs    = (const float*)d_in[0];
  const float* amask = (const float*)d_in[1];
  const float* hmask = (const float*)d_in[2];
  const uchar_t* qmask = (const uchar_t*)d_in[3];
  const float* Wq = (const float*)d_in[6];
  const float* bq = (const float*)d_in[7];
  const float* Wk = (const float*)d_in[8];
  const float* bk = (const float*)d_in[9];
  const float* Wv = (const float*)d_in[10];
  const float* bv = (const float*)d_in[11];
  const float* Wo = (const float*)d_in[12];
  const float* bo = (const float*)d_in[13];
  const float* ln1g = (const float*)d_in[14];
  const float* ln1b = (const float*)d_in[15];
  const float* W1 = (const float*)d_in[16];
  const float* b1 = (const float*)d_in[17];
  const float* W2 = (const float*)d_in[18];
  const float* b2 = (const float*)d_in[19];
  const float* ln2g = (const float*)d_in[20];
  const float* ln2b = (const float*)d_in[21];

  char* ws = (char*)d_ws;
  const size_t MB = 1024 * 1024;
  ushort_t* hsb  = (ushort_t*)(ws);                       // 16 MB [0,16)
  ushort_t* WqT  = (ushort_t*)(ws + 16 * MB);             //  2 MB
  ushort_t* WkT  = (ushort_t*)(ws + 18 * MB);
  ushort_t* WvT  = (ushort_t*)(ws + 20 * MB);
  ushort_t* WoT  = (ushort_t*)(ws + 22 * MB);
  ushort_t* W1T  = (ushort_t*)(ws + 24 * MB);             //  8 MB
  ushort_t* W2T  = (ushort_t*)(ws + 32 * MB);             //  8 MB -> ends 40
  ushort_t* qb   = (ushort_t*)(ws + 40 * MB);             // 16 MB
  ushort_t* kb   = (ushort_t*)(ws + 56 * MB);             // 16 MB
  ushort_t* vtb  = (ushort_t*)(ws + 72 * MB);             // 16 MB
  ushort_t* attb = (ushort_t*)(ws + 88 * MB);             // 16 MB
  float*    tmp  = (float*)(ws + 104 * MB);               // 32 MB -> ends 136
  float*    x1   = (float*)(ws + 40 * MB);                // reuse q/k after attention
  ushort_t* x1b  = (ushort_t*)(ws + 72 * MB);             // reuse vt after attention
  ushort_t* hb   = (ushort_t*)(ws + 136 * MB);            // 64 MB -> ends 200
  float*    outf = (float*)d_out;

  // 0) casts + weight transposes
  cast_bf16<<<(CM * CD) / 1024, 256, 0, stream>>>(hs, hsb);
  transpose_cast<<<dim3(CD / 64, CD / 64), 256, 0, stream>>>(Wq, WqT, CD, CD);
  transpose_cast<<<dim3(CD / 64, CD / 64), 256, 0, stream>>>(Wk, WkT, CD, CD);
  transpose_cast<<<dim3(CD / 64, CD / 64), 256, 0, stream>>>(Wv, WvT, CD, CD);
  transpose_cast<<<dim3(CD / 64, CD / 64), 256, 0, stream>>>(Wo, WoT, CD, CD);
  transpose_cast<<<dim3(CD / 64, CF / 64), 256, 0, stream>>>(W1, W1T, CD, CF);
  transpose_cast<<<dim3(CF / 64, CD / 64), 256, 0, stream>>>(W2, W2T, CF, CD);

  // 1) QKV projection (8-wave, BN=128)
  qkv8<<<dim3(CM / 256, CD / 128, 3), 512, 0, stream>>>(
      hsb, WqT, WkT, WvT, bq, bk, bv, qb, kb, vtb);

  // 2) sliding-window attention
  attn_mfma<<<dim3(CS / 64, CH, CB), 256, 0, stream>>>(
      qb, kb, vtb, amask, qmask, hmask, attb);

  // 3) Wo projection + residual -> tmp (fp32)
  gemm8<128, 1><<<dim3(CM / 256, CD / 128), 512, 0, stream>>>(
      attb, WoT, bo, hs, tmp, nullptr, CD, CD);

  // 4) LN1 -> x1 fp32 + x1b bf16
  ln_f32<<<CM, 256, 0, stream>>>(tmp, ln1g, ln1b, x1, x1b);

  // 5) FFN1 + GELU -> hb bf16 (8-wave, BN=256)
  gemm8<256, 2><<<dim3(CM / 256, CF / 256), 512, 0, stream>>>(
      x1b, W1T, b1, nullptr, nullptr, hb, CF, CD);

  // 6) FFN2 + residual -> d_out fp32
  gemm8<128, 1><<<dim3(CM / 256, CD / 128), 512, 0, stream>>>(
      hb, W2T, b2, x1, outf, nullptr, CD, CF);

  // 7) LN2 in place
  ln_f32<<<CM, 256, 0, stream>>>(outf, ln2g, ln2b, outf, nullptr);
}